// Round 5
// baseline (203.477 us; speedup 1.0000x reference)
//
#include <hip/hip_runtime.h>
#include <stdint.h>

// YOLO loss, round 5: stage ALL four input streams via global_load_lds,
// wave-private, double-buffered, zero direct global loads in the loop.
//  - vmcnt FIFO lesson from r4: any direct load consumed inside the loop
//    forces a drain of staging ops issued before it. So nothing is consumed
//    from registers; everything round-trips LDS via the async DMA.
//  - Per 64-cell chunk: pred 7680B (7x16 + 2x4 ops) + tcls 5120B (5x16)
//    + tbox 1024B (1x16) + mask 256B (1x4) = 16 ops, 14080 B.
//  - WAITVM(16) = s_waitcnt vmcnt(16): 6-bit vmcnt is split [15:14]|[3:0].
//    Retires current buffer's 16 ops, leaves next buffer's 16 in flight.
//  - BLOCK=128 (2 waves): LDS = 2 waves * 2 bufs * 14080 = 56320 B < 64 KB.
//    2 blocks/CU -> 4 waves/CU, 14 KB outstanding per wave continuously.

#define SS 28
#define BLOCK 128
#define WPB 2                        // waves per block
#define CPW 64                       // cells per wave-chunk
#define W_PRED 1920                  // words of pred per chunk
#define W_TCLS 1280
#define W_TBOX 256
#define W_MASK 64
#define W_BUF  (W_PRED + W_TCLS + W_TBOX + W_MASK)   // 3520 words = 14080 B
#define GRID 512                     // 2 blocks/CU resident

typedef const __attribute__((address_space(1))) void* gvp;
typedef __attribute__((address_space(3))) void* lvp;

// s_waitcnt with only vmcnt active: expcnt=7 (bits 6:4), lgkmcnt=15 (bits 11:8),
// vmcnt 6-bit split: low nibble bits 3:0, high 2 bits at 15:14.
#define WAITVM(n) __builtin_amdgcn_s_waitcnt(0x0F70 | ((n) & 0xF) | ((((n) >> 4) & 0x3) << 14))

__device__ __forceinline__ void stage_chunk(
    const float* __restrict__ pred, const float* __restrict__ tcls,
    const float* __restrict__ tboxf, const int* __restrict__ mask,
    long long chunk, float* ldsbuf, int lane)
{
    const float* sp = pred + chunk * W_PRED;
    #pragma unroll
    for (int k = 0; k < 7; ++k)
        __builtin_amdgcn_global_load_lds((gvp)(sp + k * 256 + lane * 4),
                                         (lvp)(ldsbuf + k * 256), 16, 0, 0);
    #pragma unroll
    for (int j = 0; j < 2; ++j)
        __builtin_amdgcn_global_load_lds((gvp)(sp + 1792 + j * 64 + lane),
                                         (lvp)(ldsbuf + 1792 + j * 64), 4, 0, 0);

    const float* sc = tcls + chunk * W_TCLS;
    #pragma unroll
    for (int k = 0; k < 5; ++k)
        __builtin_amdgcn_global_load_lds((gvp)(sc + k * 256 + lane * 4),
                                         (lvp)(ldsbuf + W_PRED + k * 256), 16, 0, 0);

    __builtin_amdgcn_global_load_lds((gvp)(tboxf + chunk * W_TBOX + lane * 4),
                                     (lvp)(ldsbuf + W_PRED + W_TCLS), 16, 0, 0);

    __builtin_amdgcn_global_load_lds((gvp)(mask + chunk * W_MASK + lane),
                                     (lvp)(ldsbuf + W_PRED + W_TCLS + W_TBOX), 4, 0, 0);
}

__device__ __forceinline__ void cell_loss(
    const float* __restrict__ pr,       // 30 floats in regs
    float4 tb, const float4* __restrict__ tc4, bool m,   // tc4: LDS float4 ptr
    float& acc_cls, float& acc_noobj, float& acc_reg, float& acc_cont)
{
    float fm = m ? 1.f : 0.f;

    float cls = 0.f;
    #pragma unroll
    for (int i = 0; i < 5; ++i) {
        float4 v = tc4[i];
        float d0 = pr[10 + 4 * i + 0] - v.x;
        float d1 = pr[10 + 4 * i + 1] - v.y;
        float d2 = pr[10 + 4 * i + 2] - v.z;
        float d3 = pr[10 + 4 * i + 3] - v.w;
        cls += d0 * d0 + d1 * d1 + d2 * d2 + d3 * d3;
    }
    acc_cls += fm * cls;

    acc_noobj += (1.f - fm) * (pr[4] * pr[4] + pr[9] * pr[9]);

    const float invS = 1.f / 28.f;
    float txc = tb.x * invS, tyc = tb.y * invS;
    float t0 = txc - 0.5f * tb.z, t1 = tyc - 0.5f * tb.w;
    float t2 = txc + 0.5f * tb.z, t3 = tyc + 0.5f * tb.w;
    float ta = (t2 - t0) * (t3 - t1);

    float b1xc = pr[0] * invS, b1yc = pr[1] * invS;
    float a0 = b1xc - 0.5f * pr[2], a1 = b1yc - 0.5f * pr[3];
    float a2 = b1xc + 0.5f * pr[2], a3 = b1yc + 0.5f * pr[3];
    float wx = fmaxf(fminf(a2, t2) - fmaxf(a0, t0), 0.f);
    float wy = fmaxf(fminf(a3, t3) - fmaxf(a1, t1), 0.f);
    float inter = wx * wy;
    float area1 = (a2 - a0) * (a3 - a1);
    float den = area1 + ta - inter;
    float iou1 = inter / (den > 0.f ? den : 1.f);

    float b2xc = pr[5] * invS, b2yc = pr[6] * invS;
    float c0 = b2xc - 0.5f * pr[7], c1 = b2yc - 0.5f * pr[8];
    float c2 = b2xc + 0.5f * pr[7], c3 = b2yc + 0.5f * pr[8];
    wx = fmaxf(fminf(c2, t2) - fmaxf(c0, t0), 0.f);
    wy = fmaxf(fminf(c3, t3) - fmaxf(c1, t1), 0.f);
    inter = wx * wy;
    float area2 = (c2 - c0) * (c3 - c1);
    den = area2 + ta - inter;
    float iou2 = inter / (den > 0.f ? den : 1.f);

    bool take1 = iou1 > iou2;
    float best_iou = take1 ? iou1 : iou2;
    float bbx = take1 ? pr[0] : pr[5];
    float bby = take1 ? pr[1] : pr[6];
    float bbw = take1 ? pr[2] : pr[7];
    float bbh = take1 ? pr[3] : pr[8];
    float bbc = take1 ? pr[4] : pr[9];

    float dx = bbx - tb.x, dy = bby - tb.y;
    float xy = dx * dx + dy * dy;

    float wp = m ? bbw : 1.f, hp = m ? bbh : 1.f;
    float wt = m ? tb.z : 1.f, ht = m ? tb.w : 1.f;
    float dw = sqrtf(wp) - sqrtf(wt);
    float dh = sqrtf(hp) - sqrtf(ht);
    float wh = dw * dw + dh * dh;

    acc_reg += fm * (xy + wh);

    float dc = bbc - best_iou;
    acc_cont += fm * dc * dc;
}

__global__ __launch_bounds__(BLOCK) void yolo_main(
    const float* __restrict__ pred,     // [cells*30]
    const float* __restrict__ tboxf,    // [cells*4]
    const float* __restrict__ tcls,     // [cells*20]
    const int*   __restrict__ mask,     // [cells]
    float4* __restrict__ block_part,    // [GRID]
    int nchunks, int cells)
{
    __shared__ float stage[WPB][2][W_BUF];      // 56320 B
    __shared__ float4 sred[WPB];

    const int t    = threadIdx.x;
    const int lane = t & 63;
    const int w    = t >> 6;
    const int gw   = blockIdx.x * WPB + w;
    const int nw   = GRID * WPB;

    float acc_cls = 0.f, acc_noobj = 0.f, acc_reg = 0.f, acc_cont = 0.f;

    int c = gw;
    int buf = 0;
    if (c < nchunks)
        stage_chunk(pred, tcls, tboxf, mask, (long long)c, &stage[w][0][0], lane);

    while (c < nchunks) {
        int cn = c + nw;
        if (cn < nchunks) {
            stage_chunk(pred, tcls, tboxf, mask, (long long)cn, &stage[w][buf ^ 1][0], lane);
            WAITVM(16);     // current buffer's 16 done; next buffer's 16 in flight
        } else {
            WAITVM(0);
        }

        float* b = &stage[w][buf][0];

        // pred: 15x ds_read_b64 (stride 120 B -> 4-way conflict, ~1.58x, ok)
        float pr[30];
        {
            const float2* p2 = (const float2*)(b + lane * 30);
            #pragma unroll
            for (int i = 0; i < 15; ++i) {
                float2 v = p2[i];
                pr[2 * i] = v.x; pr[2 * i + 1] = v.y;
            }
        }
        // tbox: 1x ds_read_b128
        float4 tb = *(const float4*)(b + W_PRED + W_TCLS + lane * 4);
        // mask: 1x ds_read_b32 (2-way aliasing, free)
        int mv = *(const int*)(b + W_PRED + W_TCLS + W_TBOX + lane);
        // tcls consumed as float4 directly from LDS inside cell_loss
        const float4* tc4 = (const float4*)(b + W_PRED + lane * 20);

        cell_loss(pr, tb, tc4, mv != 0, acc_cls, acc_noobj, acc_reg, acc_cont);

        buf ^= 1;
        c = cn;
    }

    // tail (cells % 64 != 0 — not hit for N=1024, kept for generality)
    int tail_base = nchunks * CPW;
    if (gw == 0 && tail_base + lane < cells) {
        int cell = tail_base + lane;
        float pr[30];
        const float2* p2 = (const float2*)(pred + (size_t)cell * 30);
        #pragma unroll
        for (int i = 0; i < 15; ++i) {
            float2 v = p2[i];
            pr[2 * i] = v.x; pr[2 * i + 1] = v.y;
        }
        float4 tbv = ((const float4*)tboxf)[cell];
        float tcbuf[20];
        #pragma unroll
        for (int i = 0; i < 20; ++i) tcbuf[i] = tcls[(size_t)cell * 20 + i];
        cell_loss(pr, tbv, (const float4*)tcbuf, mask[cell] != 0,
                  acc_cls, acc_noobj, acc_reg, acc_cont);
    }

    // wave reduction
    float4 v = make_float4(acc_cls, acc_noobj, acc_reg, acc_cont);
    #pragma unroll
    for (int off = 32; off >= 1; off >>= 1) {
        v.x += __shfl_down(v.x, off, 64);
        v.y += __shfl_down(v.y, off, 64);
        v.z += __shfl_down(v.z, off, 64);
        v.w += __shfl_down(v.w, off, 64);
    }
    if (lane == 0) sred[w] = v;
    __syncthreads();
    if (t == 0) {
        float4 r = sred[0];
        #pragma unroll
        for (int i = 1; i < WPB; ++i) {
            r.x += sred[i].x; r.y += sred[i].y; r.z += sred[i].z; r.w += sred[i].w;
        }
        block_part[blockIdx.x] = r;
    }
}

__global__ __launch_bounds__(256) void yolo_final(
    const float4* __restrict__ part, int nparts, float* __restrict__ out, float invN)
{
    float4 v = make_float4(0.f, 0.f, 0.f, 0.f);
    for (int i = threadIdx.x; i < nparts; i += 256) {
        float4 p = part[i];
        v.x += p.x; v.y += p.y; v.z += p.z; v.w += p.w;
    }
    #pragma unroll
    for (int off = 32; off >= 1; off >>= 1) {
        v.x += __shfl_down(v.x, off, 64);
        v.y += __shfl_down(v.y, off, 64);
        v.z += __shfl_down(v.z, off, 64);
        v.w += __shfl_down(v.w, off, 64);
    }
    __shared__ float4 sred[4];
    int lane = threadIdx.x & 63;
    int wave = threadIdx.x >> 6;
    if (lane == 0) sred[wave] = v;
    __syncthreads();
    if (threadIdx.x == 0) {
        float4 r = sred[0];
        #pragma unroll
        for (int w = 1; w < 4; ++w) {
            r.x += sred[w].x; r.y += sred[w].y; r.z += sred[w].z; r.w += sred[w].w;
        }
        float cls    = r.x;
        float no_obj = 0.5f * r.y;   // L_NOOBJ
        float reg    = 5.0f * r.z;   // L_COORD
        float cont   = r.w;
        float total  = cls + no_obj + cont + reg;
        out[0] = total  * invN;
        out[1] = reg    * invN;
        out[2] = cont   * invN;
        out[3] = no_obj * invN;
        out[4] = cls    * invN;
    }
}

extern "C" void kernel_launch(void* const* d_in, const int* in_sizes, int n_in,
                              void* d_out, int out_size, void* d_ws, size_t ws_size,
                              hipStream_t stream) {
    const float* pred = (const float*)d_in[0];
    const float* tbox = (const float*)d_in[1];
    const float* tcls = (const float*)d_in[2];
    const int*   mask = (const int*)d_in[3];
    float* out = (float*)d_out;

    int cells   = in_sizes[0] / 30;        // N*S*S
    int n_img   = cells / (SS * SS);       // N
    int nchunks = cells / CPW;             // 12544, exact for N=1024

    float4* part = (float4*)d_ws;          // GRID * 16 bytes

    yolo_main<<<GRID, BLOCK, 0, stream>>>(
        pred, tbox, tcls, mask, part, nchunks, cells);
    yolo_final<<<1, 256, 0, stream>>>(part, GRID, out, 1.0f / (float)n_img);
}

// Round 6
// 198.613 us; speedup vs baseline: 1.0245x; 1.0245x over previous
//
#include <hip/hip_runtime.h>

// YOLO loss, round 6: mask-gated loads.
// Evidence r1-r5: four structures, occupancy 9%-52%, all exactly ~68us ->
// shared memory-system service cap (~2.6 TB/s for this mix), not a CU-side
// limit. Only remaining lever: request fewer bytes. For mask=0 cells (70%)
// the reference needs ONLY pred[4], pred[9] (no_obj term); tcls (80 B) and
// tbox (16 B) are dead. Per-lane exec-masked gating skips those requests.
// Demand: 176.6 MB -> ~137 MB.

#define SS 28
#define BLOCK 256

__global__ __launch_bounds__(BLOCK) void yolo_main(
    const float* __restrict__ pred,     // [cells*30]
    const float4* __restrict__ tbox4,   // [cells]
    const float4* __restrict__ tcls4,   // [cells*5]
    const int*   __restrict__ mask,     // [cells]
    float4* __restrict__ block_part,    // [gridDim.x]
    int cells)
{
    int cell = blockIdx.x * BLOCK + threadIdx.x;

    float acc_cls = 0.f, acc_noobj = 0.f, acc_reg = 0.f, acc_cont = 0.f;

    if (cell < cells) {
        bool m = mask[cell] != 0;               // coalesced 4B
        const float* pc = pred + (size_t)cell * 30;

        if (!m) {
            // only the confidence terms are live
            float c1 = pc[4];
            float c2 = pc[9];
            acc_noobj = c1 * c1 + c2 * c2;      // *0.5 in finalize
        } else {
            // full record needed
            float pr[30];
            const float2* p2 = (const float2*)pc;      // 8B-aligned (cell*120B)
            #pragma unroll
            for (int i = 0; i < 15; ++i) {
                float2 v = p2[i];
                pr[2 * i] = v.x; pr[2 * i + 1] = v.y;
            }
            float4 tb = tbox4[cell];

            // class loss: stream tcls, consume immediately
            {
                const float4* t4 = tcls4 + (size_t)cell * 5;
                float cls = 0.f;
                #pragma unroll
                for (int i = 0; i < 5; ++i) {
                    float4 v = t4[i];
                    float d0 = pr[10 + 4 * i + 0] - v.x;
                    float d1 = pr[10 + 4 * i + 1] - v.y;
                    float d2 = pr[10 + 4 * i + 2] - v.z;
                    float d3 = pr[10 + 4 * i + 3] - v.w;
                    cls += d0 * d0 + d1 * d1 + d2 * d2 + d3 * d3;
                }
                acc_cls = cls;
            }

            // IOU, exact reference arithmetic
            const float invS = 1.f / 28.f;
            float txc = tb.x * invS, tyc = tb.y * invS;
            float t0 = txc - 0.5f * tb.z, t1 = tyc - 0.5f * tb.w;
            float t2 = txc + 0.5f * tb.z, t3 = tyc + 0.5f * tb.w;
            float ta = (t2 - t0) * (t3 - t1);

            float b1xc = pr[0] * invS, b1yc = pr[1] * invS;
            float a0 = b1xc - 0.5f * pr[2], a1 = b1yc - 0.5f * pr[3];
            float a2 = b1xc + 0.5f * pr[2], a3 = b1yc + 0.5f * pr[3];
            float wx = fmaxf(fminf(a2, t2) - fmaxf(a0, t0), 0.f);
            float wy = fmaxf(fminf(a3, t3) - fmaxf(a1, t1), 0.f);
            float inter = wx * wy;
            float area1 = (a2 - a0) * (a3 - a1);
            float den = area1 + ta - inter;
            float iou1 = inter / (den > 0.f ? den : 1.f);

            float b2xc = pr[5] * invS, b2yc = pr[6] * invS;
            float c0 = b2xc - 0.5f * pr[7], c1 = b2yc - 0.5f * pr[8];
            float c2 = b2xc + 0.5f * pr[7], c3 = b2yc + 0.5f * pr[8];
            wx = fmaxf(fminf(c2, t2) - fmaxf(c0, t0), 0.f);
            wy = fmaxf(fminf(c3, t3) - fmaxf(c1, t1), 0.f);
            inter = wx * wy;
            float area2 = (c2 - c0) * (c3 - c1);
            den = area2 + ta - inter;
            float iou2 = inter / (den > 0.f ? den : 1.f);

            bool take1 = iou1 > iou2;
            float best_iou = take1 ? iou1 : iou2;
            float bbx = take1 ? pr[0] : pr[5];
            float bby = take1 ? pr[1] : pr[6];
            float bbw = take1 ? pr[2] : pr[7];
            float bbh = take1 ? pr[3] : pr[8];
            float bbc = take1 ? pr[4] : pr[9];

            float dx = bbx - tb.x, dy = bby - tb.y;
            float xy = dx * dx + dy * dy;

            // m==1 here: where(mask, v, 1.0) == v
            float dw = sqrtf(bbw) - sqrtf(tb.z);
            float dh = sqrtf(bbh) - sqrtf(tb.w);
            float wh = dw * dw + dh * dh;

            acc_reg = xy + wh;

            float dc = bbc - best_iou;
            acc_cont = dc * dc;
        }
    }

    // wave reduction (64 lanes)
    float4 v = make_float4(acc_cls, acc_noobj, acc_reg, acc_cont);
    #pragma unroll
    for (int off = 32; off >= 1; off >>= 1) {
        v.x += __shfl_down(v.x, off, 64);
        v.y += __shfl_down(v.y, off, 64);
        v.z += __shfl_down(v.z, off, 64);
        v.w += __shfl_down(v.w, off, 64);
    }
    __shared__ float4 sred[BLOCK / 64];
    int lane = threadIdx.x & 63;
    int wave = threadIdx.x >> 6;
    if (lane == 0) sred[wave] = v;
    __syncthreads();
    if (threadIdx.x == 0) {
        float4 r = sred[0];
        #pragma unroll
        for (int w = 1; w < BLOCK / 64; ++w) {
            r.x += sred[w].x; r.y += sred[w].y; r.z += sred[w].z; r.w += sred[w].w;
        }
        block_part[blockIdx.x] = r;
    }
}

__global__ __launch_bounds__(BLOCK) void yolo_final(
    const float4* __restrict__ part, int nparts, float* __restrict__ out, float invN)
{
    float4 v = make_float4(0.f, 0.f, 0.f, 0.f);
    for (int i = threadIdx.x; i < nparts; i += BLOCK) {
        float4 p = part[i];
        v.x += p.x; v.y += p.y; v.z += p.z; v.w += p.w;
    }
    #pragma unroll
    for (int off = 32; off >= 1; off >>= 1) {
        v.x += __shfl_down(v.x, off, 64);
        v.y += __shfl_down(v.y, off, 64);
        v.z += __shfl_down(v.z, off, 64);
        v.w += __shfl_down(v.w, off, 64);
    }
    __shared__ float4 sred[BLOCK / 64];
    int lane = threadIdx.x & 63;
    int wave = threadIdx.x >> 6;
    if (lane == 0) sred[wave] = v;
    __syncthreads();
    if (threadIdx.x == 0) {
        float4 r = sred[0];
        #pragma unroll
        for (int w = 1; w < BLOCK / 64; ++w) {
            r.x += sred[w].x; r.y += sred[w].y; r.z += sred[w].z; r.w += sred[w].w;
        }
        float cls    = r.x;
        float no_obj = 0.5f * r.y;   // L_NOOBJ
        float reg    = 5.0f * r.z;   // L_COORD
        float cont   = r.w;
        float total  = cls + no_obj + cont + reg;
        out[0] = total  * invN;
        out[1] = reg    * invN;
        out[2] = cont   * invN;
        out[3] = no_obj * invN;
        out[4] = cls    * invN;
    }
}

extern "C" void kernel_launch(void* const* d_in, const int* in_sizes, int n_in,
                              void* d_out, int out_size, void* d_ws, size_t ws_size,
                              hipStream_t stream) {
    const float* pred = (const float*)d_in[0];
    const float* tbox = (const float*)d_in[1];
    const float* tcls = (const float*)d_in[2];
    const int*   mask = (const int*)d_in[3];
    float* out = (float*)d_out;

    int cells = in_sizes[0] / 30;                 // N*S*S = 802816
    int n_img = cells / (SS * SS);                // N
    int nblocks = (cells + BLOCK - 1) / BLOCK;    // 3136

    float4* part = (float4*)d_ws;                 // nblocks * 16 bytes

    yolo_main<<<nblocks, BLOCK, 0, stream>>>(
        pred, (const float4*)tbox, (const float4*)tcls, mask, part, cells);
    yolo_final<<<1, BLOCK, 0, stream>>>(part, nblocks, out, 1.0f / (float)n_img);
}